// Round 1
// baseline (361.483 us; speedup 1.0000x reference)
//
#include <hip/hip_runtime.h>

// ---------------------------------------------------------------------------
// 3-layer GCN: h = relu(Agg(x@W1)+b1); h = relu(Agg(h@W2)+b2); out = Agg(h@W3)+b3
// Agg(m)[i] = dinv[i] * ( dinv[i]*m[i](self) + sum_{e: dst=i} dinv[src]*m[src] )
// Factorized: tmp[n] = dinv[n]*(h[n]@W);  agg[i] = dinv[i]*(tmp[i] + sum tmp[src]) + b
// ---------------------------------------------------------------------------

// ---------------- CSR build ----------------

__global__ __launch_bounds__(256) void count_kernel(const int* __restrict__ dst,
                                                    int* __restrict__ cnt, int E) {
    int e = blockIdx.x * 256 + threadIdx.x;
    if (e < E) atomicAdd(&cnt[dst[e]], 1);
}

__global__ __launch_bounds__(256) void dinv_kernel(const int* __restrict__ cnt,
                                                   float* __restrict__ dinv, int M) {
    int i = blockIdx.x * 256 + threadIdx.x;
    if (i < M) dinv[i] = 1.0f / sqrtf((float)cnt[i] + 1.0f);  // +1: self-loop
}

// block-local exclusive scan of cnt -> loc; per-block total -> bsum
__global__ __launch_bounds__(256) void scan1_kernel(const int* __restrict__ cnt,
                                                    int* __restrict__ loc,
                                                    int* __restrict__ bsum, int M) {
    __shared__ int sm[256];
    int t = threadIdx.x;
    int i = blockIdx.x * 256 + t;
    int v = (i < M) ? cnt[i] : 0;
    sm[t] = v;
    __syncthreads();
    for (int o = 1; o < 256; o <<= 1) {
        int add = (t >= o) ? sm[t - o] : 0;
        __syncthreads();
        sm[t] += add;
        __syncthreads();
    }
    if (i < M) loc[i] = sm[t] - v;              // exclusive
    if (t == 255) bsum[blockIdx.x] = sm[255];   // inclusive total
}

// single block: exclusive scan of bsum in-place (NB <= 256)
__global__ __launch_bounds__(256) void scan2_kernel(int* __restrict__ bsum, int NB) {
    __shared__ int sm[256];
    int t = threadIdx.x;
    int v = (t < NB) ? bsum[t] : 0;
    sm[t] = v;
    __syncthreads();
    for (int o = 1; o < 256; o <<= 1) {
        int add = (t >= o) ? sm[t - o] : 0;
        __syncthreads();
        sm[t] += add;
        __syncthreads();
    }
    if (t < NB) bsum[t] = sm[t] - v;
}

__global__ __launch_bounds__(256) void place_kernel(const int* __restrict__ src,
                                                    const int* __restrict__ dst,
                                                    const int* __restrict__ loc,
                                                    const int* __restrict__ base,
                                                    int* __restrict__ fill,
                                                    int* __restrict__ srcs, int E) {
    int e = blockIdx.x * 256 + threadIdx.x;
    if (e >= E) return;
    int d = dst[e];
    int pos = loc[d] + base[d >> 8] + atomicAdd(&fill[d], 1);
    srcs[pos] = src[e];
}

// ---------------- GEMM: out[m][c] = dinv[m] * sum_k A[m][k] * W[k][c] ----------------

template <int K, int C>
__global__ __launch_bounds__(256) void gemm_scale_kernel(const float* __restrict__ A,
                                                         const float* __restrict__ W,
                                                         const float* __restrict__ dinv,
                                                         float* __restrict__ out, int M) {
    constexpr int CT = C / 4;         // threads across columns (each owns 4 cols)
    constexpr int RT = 256 / CT;      // thread rows (each owns 4 rows)
    constexpr int TM = RT * 4;        // rows per block
    constexpr int KB = 32;            // k-chunk
    constexpr int AP = TM + 4;        // padded row stride (keeps 16B alignment, breaks pow2)

    __shared__ __align__(16) float Ast[KB][AP];   // A tile, transposed: Ast[k][row]
    __shared__ __align__(16) float Bs[KB][C];

    const int t = threadIdx.x;
    const int tx = t % CT;
    const int ty = t / CT;
    const int row0 = blockIdx.x * TM;

    float acc[4][4];
#pragma unroll
    for (int i = 0; i < 4; i++)
#pragma unroll
        for (int j = 0; j < 4; j++) acc[i][j] = 0.f;

    constexpr int ALOADS = (TM * KB) / (256 * 4);  // float4 loads of A per thread
    constexpr int BLOADS = (KB * C) / (256 * 4);   // float4 loads of W per thread

    for (int k0 = 0; k0 < K; k0 += KB) {
#pragma unroll
        for (int l = 0; l < ALOADS; l++) {
            int idx = t + l * 256;
            int ar = idx >> 3;            // row within tile (8 float4 per row of 32 k)
            int kq = (idx & 7) * 4;       // k offset
            int grow = row0 + ar;
            float4 v = make_float4(0.f, 0.f, 0.f, 0.f);
            if (grow < M) v = *(const float4*)(A + (size_t)grow * K + k0 + kq);
            Ast[kq + 0][ar] = v.x;
            Ast[kq + 1][ar] = v.y;
            Ast[kq + 2][ar] = v.z;
            Ast[kq + 3][ar] = v.w;
        }
#pragma unroll
        for (int l = 0; l < BLOADS; l++) {
            int idx = t + l * 256;
            int bk = idx / (C / 4);
            int bc = (idx % (C / 4)) * 4;
            *(float4*)(&Bs[bk][bc]) = *(const float4*)(W + (size_t)(k0 + bk) * C + bc);
        }
        __syncthreads();
#pragma unroll
        for (int k = 0; k < KB; k++) {
            float4 a = *(const float4*)(&Ast[k][ty * 4]);
            float4 b = *(const float4*)(&Bs[k][tx * 4]);
            acc[0][0] += a.x * b.x; acc[0][1] += a.x * b.y; acc[0][2] += a.x * b.z; acc[0][3] += a.x * b.w;
            acc[1][0] += a.y * b.x; acc[1][1] += a.y * b.y; acc[1][2] += a.y * b.z; acc[1][3] += a.y * b.w;
            acc[2][0] += a.z * b.x; acc[2][1] += a.z * b.y; acc[2][2] += a.z * b.z; acc[2][3] += a.z * b.w;
            acc[3][0] += a.w * b.x; acc[3][1] += a.w * b.y; acc[3][2] += a.w * b.z; acc[3][3] += a.w * b.w;
        }
        __syncthreads();
    }
#pragma unroll
    for (int i = 0; i < 4; i++) {
        int r = row0 + ty * 4 + i;
        if (r < M) {
            float dv = dinv[r];
            float4 v = make_float4(acc[i][0] * dv, acc[i][1] * dv, acc[i][2] * dv, acc[i][3] * dv);
            *(float4*)(out + (size_t)r * C + tx * 4) = v;
        }
    }
}

// ---------------- Aggregation: out[i] = act(dinv[i]*(tmp[i] + sum tmp[src]) + b) ----------------

template <int C, bool RELU>
__global__ __launch_bounds__(256) void agg_kernel(const float* __restrict__ tmp,
                                                  const int* __restrict__ srcs,
                                                  const int* __restrict__ cnt,
                                                  const int* __restrict__ loc,
                                                  const int* __restrict__ base,
                                                  const float* __restrict__ dinv,
                                                  const float* __restrict__ bias,
                                                  float* __restrict__ out, int M) {
    constexpr int TPN = C / 4;        // threads per node (float4 per thread)
    constexpr int NPB = 256 / TPN;    // nodes per block
    const int t = threadIdx.x;
    const int cq = t % TPN;
    const int node = blockIdx.x * NPB + t / TPN;
    if (node >= M) return;

    const float4* tmp4 = (const float4*)tmp;
    float4 acc = tmp4[(size_t)node * TPN + cq];   // self-loop term
    const int start = loc[node] + base[node >> 8];
    const int n = cnt[node];

    int s = (n > 0) ? srcs[start] : 0;
    for (int j = 0; j < n; ++j) {
        int snext = (j + 1 < n) ? srcs[start + j + 1] : 0;
        float4 v = tmp4[(size_t)s * TPN + cq];
        acc.x += v.x; acc.y += v.y; acc.z += v.z; acc.w += v.w;
        s = snext;
    }

    float dv = dinv[node];
    float4 b = *(const float4*)(bias + cq * 4);
    float4 r;
    r.x = acc.x * dv + b.x;
    r.y = acc.y * dv + b.y;
    r.z = acc.z * dv + b.z;
    r.w = acc.w * dv + b.w;
    if (RELU) {
        r.x = fmaxf(r.x, 0.f); r.y = fmaxf(r.y, 0.f);
        r.z = fmaxf(r.z, 0.f); r.w = fmaxf(r.w, 0.f);
    }
    ((float4*)out)[(size_t)node * TPN + cq] = r;
}

// ---------------- launch ----------------

extern "C" void kernel_launch(void* const* d_in, const int* in_sizes, int n_in,
                              void* d_out, int out_size, void* d_ws, size_t ws_size,
                              hipStream_t stream) {
    const float* x  = (const float*)d_in[0];
    const int*   ei = (const int*)d_in[1];
    const float* W1 = (const float*)d_in[2];
    const float* b1 = (const float*)d_in[3];
    const float* W2 = (const float*)d_in[4];
    const float* b2 = (const float*)d_in[5];
    const float* W3 = (const float*)d_in[6];
    const float* b3 = (const float*)d_in[7];
    float* out = (float*)d_out;

    const int M = in_sizes[0] / 256;   // 50000 nodes
    const int E = in_sizes[1] / 2;     // 800000 edges
    const int NB = (M + 255) / 256;

    char* p = (char*)d_ws;
    auto alloc = [&](size_t bytes) {
        char* r = p;
        p += (bytes + 255) & ~(size_t)255;
        return r;
    };
    int*   cnt  = (int*)alloc((size_t)M * 4);
    int*   fill = (int*)alloc((size_t)M * 4);
    int*   loc  = (int*)alloc((size_t)M * 4);
    int*   base = (int*)alloc((size_t)NB * 4);
    float* dinv = (float*)alloc((size_t)M * 4);
    int*   srcs = (int*)alloc((size_t)E * 4);
    float* tmp  = (float*)alloc((size_t)M * 128 * 4);
    float* h    = (float*)alloc((size_t)M * 128 * 4);

    hipMemsetAsync(cnt, 0, (size_t)M * 4, stream);
    hipMemsetAsync(fill, 0, (size_t)M * 4, stream);

    const int* esrc = ei;
    const int* edst = ei + E;

    count_kernel<<<(E + 255) / 256, 256, 0, stream>>>(edst, cnt, E);
    dinv_kernel<<<(M + 255) / 256, 256, 0, stream>>>(cnt, dinv, M);
    scan1_kernel<<<NB, 256, 0, stream>>>(cnt, loc, base, M);
    scan2_kernel<<<1, 256, 0, stream>>>(base, NB);
    place_kernel<<<(E + 255) / 256, 256, 0, stream>>>(esrc, edst, loc, base, fill, srcs, E);

    // layer 1: x[50000,256] @ W1[256,128] -> relu agg -> h
    gemm_scale_kernel<256, 128><<<(M + 31) / 32, 256, 0, stream>>>(x, W1, dinv, tmp, M);
    agg_kernel<128, true><<<(M + 1) / 2, 256, 0, stream>>>(tmp, srcs, cnt, loc, base, dinv, b1, h, M);

    // layer 2: h @ W2[128,128] -> relu agg -> h
    gemm_scale_kernel<128, 128><<<(M + 31) / 32, 256, 0, stream>>>(h, W2, dinv, tmp, M);
    agg_kernel<128, true><<<(M + 1) / 2, 256, 0, stream>>>(tmp, srcs, cnt, loc, base, dinv, b2, h, M);

    // layer 3: h @ W3[128,64] -> agg -> out
    gemm_scale_kernel<128, 64><<<(M + 63) / 64, 256, 0, stream>>>(h, W3, dinv, tmp, M);
    agg_kernel<64, false><<<(M + 3) / 4, 256, 0, stream>>>(tmp, srcs, cnt, loc, base, dinv, b3, out, M);
}

// Round 2
// 337.936 us; speedup vs baseline: 1.0697x; 1.0697x over previous
//
#include <hip/hip_runtime.h>

// ---------------------------------------------------------------------------
// 3-layer GCN: h = relu(Agg(x@W1)+b1); h = relu(Agg(h@W2)+b2); out = Agg(h@W3)+b3
// Agg(m)[i] = dinv[i] * ( dinv[i]*m[i](self) + sum_{e: dst=i} dinv[src]*m[src] )
// Factorized: tmp[n] = dinv[n]*(h[n]@W);  agg[i] = dinv[i]*(tmp[i] + sum tmp[src]) + b
// All fp32: max|ref| ~ 488 with threshold 5.2e-3 (1e-5 relative) forbids bf16.
// ---------------------------------------------------------------------------

// ---------------- CSR build ----------------

__global__ __launch_bounds__(256) void count_kernel(const int* __restrict__ dst,
                                                    int* __restrict__ cnt, int E) {
    int e = blockIdx.x * 256 + threadIdx.x;
    if (e < E) atomicAdd(&cnt[dst[e]], 1);
}

__global__ __launch_bounds__(256) void dinv_kernel(const int* __restrict__ cnt,
                                                   float* __restrict__ dinv, int M) {
    int i = blockIdx.x * 256 + threadIdx.x;
    if (i < M) dinv[i] = 1.0f / sqrtf((float)cnt[i] + 1.0f);  // +1: self-loop
}

// block-local exclusive scan of cnt -> loc; per-block total -> bsum
__global__ __launch_bounds__(256) void scan1_kernel(const int* __restrict__ cnt,
                                                    int* __restrict__ loc,
                                                    int* __restrict__ bsum, int M) {
    __shared__ int sm[256];
    int t = threadIdx.x;
    int i = blockIdx.x * 256 + t;
    int v = (i < M) ? cnt[i] : 0;
    sm[t] = v;
    __syncthreads();
    for (int o = 1; o < 256; o <<= 1) {
        int add = (t >= o) ? sm[t - o] : 0;
        __syncthreads();
        sm[t] += add;
        __syncthreads();
    }
    if (i < M) loc[i] = sm[t] - v;              // exclusive
    if (t == 255) bsum[blockIdx.x] = sm[255];   // inclusive total
}

// single block: exclusive scan of bsum in-place (NB <= 256)
__global__ __launch_bounds__(256) void scan2_kernel(int* __restrict__ bsum, int NB) {
    __shared__ int sm[256];
    int t = threadIdx.x;
    int v = (t < NB) ? bsum[t] : 0;
    sm[t] = v;
    __syncthreads();
    for (int o = 1; o < 256; o <<= 1) {
        int add = (t >= o) ? sm[t - o] : 0;
        __syncthreads();
        sm[t] += add;
        __syncthreads();
    }
    if (t < NB) bsum[t] = sm[t] - v;
}

__global__ __launch_bounds__(256) void place_kernel(const int* __restrict__ src,
                                                    const int* __restrict__ dst,
                                                    const int* __restrict__ loc,
                                                    const int* __restrict__ base,
                                                    int* __restrict__ fill,
                                                    int* __restrict__ srcs, int E) {
    int e = blockIdx.x * 256 + threadIdx.x;
    if (e >= E) return;
    int d = dst[e];
    int pos = loc[d] + base[d >> 8] + atomicAdd(&fill[d], 1);
    srcs[pos] = src[e];
}

// ---------------- GEMM: out[m][c] = dinv[m] * sum_k A[m][k] * W[k][c] ----------------
// 8 rows x 4 cols per thread; 256 threads -> (64*CT/32) rows x C cols per block.

template <int K, int C>
__global__ __launch_bounds__(256) void gemm_scale_kernel(const float* __restrict__ A,
                                                         const float* __restrict__ W,
                                                         const float* __restrict__ dinv,
                                                         float* __restrict__ out, int M) {
    constexpr int CT = C / 4;         // threads across columns (each owns 4 cols)
    constexpr int RT = 256 / CT;      // thread rows
    constexpr int RPT = 8;            // rows per thread
    constexpr int TM = RT * RPT;      // rows per block (64 for C=128, 128 for C=64)
    constexpr int KB = 32;            // k-chunk
    constexpr int AP = TM + 4;        // padded row stride (16B-aligned, breaks pow2)

    __shared__ __align__(16) float Ast[KB][AP];   // A tile, transposed: Ast[k][row]
    __shared__ __align__(16) float Bs[KB][C];

    const int t = threadIdx.x;
    const int tx = t % CT;
    const int ty = t / CT;
    const int row0 = blockIdx.x * TM;

    float acc[RPT][4];
#pragma unroll
    for (int i = 0; i < RPT; i++)
#pragma unroll
        for (int j = 0; j < 4; j++) acc[i][j] = 0.f;

    constexpr int ALOADS = (TM * KB) / (256 * 4);  // float4 loads of A per thread
    constexpr int BLOADS = (KB * C) / (256 * 4);   // float4 loads of W per thread

    for (int k0 = 0; k0 < K; k0 += KB) {
#pragma unroll
        for (int l = 0; l < ALOADS; l++) {
            int idx = t + l * 256;
            int ar = idx >> 3;            // row within tile (8 float4 per 32-k row)
            int kq = (idx & 7) * 4;       // k offset
            int grow = row0 + ar;
            float4 v = make_float4(0.f, 0.f, 0.f, 0.f);
            if (grow < M) v = *(const float4*)(A + (size_t)grow * K + k0 + kq);
            Ast[kq + 0][ar] = v.x;
            Ast[kq + 1][ar] = v.y;
            Ast[kq + 2][ar] = v.z;
            Ast[kq + 3][ar] = v.w;
        }
#pragma unroll
        for (int l = 0; l < BLOADS; l++) {
            int idx = t + l * 256;
            int bk = idx / (C / 4);
            int bc = (idx % (C / 4)) * 4;
            *(float4*)(&Bs[bk][bc]) = *(const float4*)(W + (size_t)(k0 + bk) * C + bc);
        }
        __syncthreads();
#pragma unroll
        for (int k = 0; k < KB; k++) {
            float4 a0 = *(const float4*)(&Ast[k][ty * RPT]);
            float4 a1 = *(const float4*)(&Ast[k][ty * RPT + 4]);
            float4 b  = *(const float4*)(&Bs[k][tx * 4]);
            acc[0][0] += a0.x * b.x; acc[0][1] += a0.x * b.y; acc[0][2] += a0.x * b.z; acc[0][3] += a0.x * b.w;
            acc[1][0] += a0.y * b.x; acc[1][1] += a0.y * b.y; acc[1][2] += a0.y * b.z; acc[1][3] += a0.y * b.w;
            acc[2][0] += a0.z * b.x; acc[2][1] += a0.z * b.y; acc[2][2] += a0.z * b.z; acc[2][3] += a0.z * b.w;
            acc[3][0] += a0.w * b.x; acc[3][1] += a0.w * b.y; acc[3][2] += a0.w * b.z; acc[3][3] += a0.w * b.w;
            acc[4][0] += a1.x * b.x; acc[4][1] += a1.x * b.y; acc[4][2] += a1.x * b.z; acc[4][3] += a1.x * b.w;
            acc[5][0] += a1.y * b.x; acc[5][1] += a1.y * b.y; acc[5][2] += a1.y * b.z; acc[5][3] += a1.y * b.w;
            acc[6][0] += a1.z * b.x; acc[6][1] += a1.z * b.y; acc[6][2] += a1.z * b.z; acc[6][3] += a1.z * b.w;
            acc[7][0] += a1.w * b.x; acc[7][1] += a1.w * b.y; acc[7][2] += a1.w * b.z; acc[7][3] += a1.w * b.w;
        }
        __syncthreads();
    }
#pragma unroll
    for (int i = 0; i < RPT; i++) {
        int r = row0 + ty * RPT + i;
        if (r < M) {
            float dv = dinv[r];
            float4 v = make_float4(acc[i][0] * dv, acc[i][1] * dv, acc[i][2] * dv, acc[i][3] * dv);
            *(float4*)(out + (size_t)r * C + tx * 4) = v;
        }
    }
}

// ---------------- Aggregation: out[i] = act(dinv[i]*(tmp[i] + sum tmp[src]) + b) ----------------
// Unroll x4 with index prefetch: 4 independent gathers in flight per thread.

template <int C, bool RELU>
__global__ __launch_bounds__(256) void agg_kernel(const float* __restrict__ tmp,
                                                  const int* __restrict__ srcs,
                                                  const int* __restrict__ cnt,
                                                  const int* __restrict__ loc,
                                                  const int* __restrict__ base,
                                                  const float* __restrict__ dinv,
                                                  const float* __restrict__ bias,
                                                  float* __restrict__ out, int M) {
    constexpr int TPN = C / 4;        // threads per node (float4 per thread)
    constexpr int NPB = 256 / TPN;    // nodes per block
    const int t = threadIdx.x;
    const int cq = t % TPN;
    const int node = blockIdx.x * NPB + t / TPN;
    if (node >= M) return;

    const float4* tmp4 = (const float4*)tmp;
    float4 acc = tmp4[(size_t)node * TPN + cq];   // self-loop term
    float4 acc2 = make_float4(0.f, 0.f, 0.f, 0.f);
    const int start = loc[node] + base[node >> 8];
    const int n = cnt[node];
    const int* sp = srcs + start;

    const int jn = n & ~3;
    int s0 = 0, s1 = 0, s2 = 0, s3 = 0;
    if (jn > 0) { s0 = sp[0]; s1 = sp[1]; s2 = sp[2]; s3 = sp[3]; }
    for (int j = 0; j < jn; j += 4) {
        float4 v0 = tmp4[(size_t)s0 * TPN + cq];
        float4 v1 = tmp4[(size_t)s1 * TPN + cq];
        float4 v2 = tmp4[(size_t)s2 * TPN + cq];
        float4 v3 = tmp4[(size_t)s3 * TPN + cq];
        if (j + 4 < jn) {
            s0 = sp[j + 4]; s1 = sp[j + 5]; s2 = sp[j + 6]; s3 = sp[j + 7];
        }
        acc.x  += v0.x + v1.x;  acc.y  += v0.y + v1.y;
        acc.z  += v0.z + v1.z;  acc.w  += v0.w + v1.w;
        acc2.x += v2.x + v3.x;  acc2.y += v2.y + v3.y;
        acc2.z += v2.z + v3.z;  acc2.w += v2.w + v3.w;
    }
    for (int j = jn; j < n; ++j) {
        float4 v = tmp4[(size_t)sp[j] * TPN + cq];
        acc.x += v.x; acc.y += v.y; acc.z += v.z; acc.w += v.w;
    }
    acc.x += acc2.x; acc.y += acc2.y; acc.z += acc2.z; acc.w += acc2.w;

    float dv = dinv[node];
    float4 b = *(const float4*)(bias + cq * 4);
    float4 r;
    r.x = acc.x * dv + b.x;
    r.y = acc.y * dv + b.y;
    r.z = acc.z * dv + b.z;
    r.w = acc.w * dv + b.w;
    if (RELU) {
        r.x = fmaxf(r.x, 0.f); r.y = fmaxf(r.y, 0.f);
        r.z = fmaxf(r.z, 0.f); r.w = fmaxf(r.w, 0.f);
    }
    ((float4*)out)[(size_t)node * TPN + cq] = r;
}

// ---------------- launch ----------------

extern "C" void kernel_launch(void* const* d_in, const int* in_sizes, int n_in,
                              void* d_out, int out_size, void* d_ws, size_t ws_size,
                              hipStream_t stream) {
    const float* x  = (const float*)d_in[0];
    const int*   ei = (const int*)d_in[1];
    const float* W1 = (const float*)d_in[2];
    const float* b1 = (const float*)d_in[3];
    const float* W2 = (const float*)d_in[4];
    const float* b2 = (const float*)d_in[5];
    const float* W3 = (const float*)d_in[6];
    const float* b3 = (const float*)d_in[7];
    float* out = (float*)d_out;

    const int M = in_sizes[0] / 256;   // 50000 nodes
    const int E = in_sizes[1] / 2;     // 800000 edges
    const int NB = (M + 255) / 256;

    char* p = (char*)d_ws;
    auto alloc = [&](size_t bytes) {
        char* r = p;
        p += (bytes + 255) & ~(size_t)255;
        return r;
    };
    int*   cnt  = (int*)alloc((size_t)M * 4);
    int*   fill = (int*)alloc((size_t)M * 4);
    int*   loc  = (int*)alloc((size_t)M * 4);
    int*   base = (int*)alloc((size_t)NB * 4);
    float* dinv = (float*)alloc((size_t)M * 4);
    int*   srcs = (int*)alloc((size_t)E * 4);
    float* tmp  = (float*)alloc((size_t)M * 128 * 4);
    float* h    = (float*)alloc((size_t)M * 128 * 4);

    hipMemsetAsync(cnt, 0, (size_t)M * 4, stream);
    hipMemsetAsync(fill, 0, (size_t)M * 4, stream);

    const int* esrc = ei;
    const int* edst = ei + E;

    count_kernel<<<(E + 255) / 256, 256, 0, stream>>>(edst, cnt, E);
    dinv_kernel<<<(M + 255) / 256, 256, 0, stream>>>(cnt, dinv, M);
    scan1_kernel<<<NB, 256, 0, stream>>>(cnt, loc, base, M);
    scan2_kernel<<<1, 256, 0, stream>>>(base, NB);
    place_kernel<<<(E + 255) / 256, 256, 0, stream>>>(esrc, edst, loc, base, fill, srcs, E);

    // layer 1: x[50000,256] @ W1[256,128] -> relu agg -> h
    gemm_scale_kernel<256, 128><<<(M + 63) / 64, 256, 0, stream>>>(x, W1, dinv, tmp, M);
    agg_kernel<128, true><<<(M + 1) / 2, 256, 0, stream>>>(tmp, srcs, cnt, loc, base, dinv, b1, h, M);

    // layer 2: h @ W2[128,128] -> relu agg -> h
    gemm_scale_kernel<128, 128><<<(M + 63) / 64, 256, 0, stream>>>(h, W2, dinv, tmp, M);
    agg_kernel<128, true><<<(M + 1) / 2, 256, 0, stream>>>(tmp, srcs, cnt, loc, base, dinv, b2, h, M);

    // layer 3: h @ W3[128,64] -> agg -> out
    gemm_scale_kernel<128, 64><<<(M + 127) / 128, 256, 0, stream>>>(h, W3, dinv, tmp, M);
    agg_kernel<64, false><<<(M + 3) / 4, 256, 0, stream>>>(tmp, srcs, cnt, loc, base, dinv, b3, out, M);
}